// Round 4
// baseline (168.941 us; speedup 1.0000x reference)
//
#include <hip/hip_runtime.h>
#include <hip/hip_bf16.h>
#include <math.h>

typedef __bf16 bf16x8 __attribute__((ext_vector_type(8)));
typedef float  f32x4  __attribute__((ext_vector_type(4)));

#define M_DIM 16384
#define N_DIM 512
#define K_DIM 512
#define TBL_N 1024

__device__ inline bf16x8 cvt8(float4 a, float4 b) {
    bf16x8 r;
    r[0] = (__bf16)a.x; r[1] = (__bf16)a.y; r[2] = (__bf16)a.z; r[3] = (__bf16)a.w;
    r[4] = (__bf16)b.x; r[5] = (__bf16)b.y; r[6] = (__bf16)b.z; r[7] = (__bf16)b.w;
    return r;
}

__device__ inline void gl_lds16(const float* g, float* l) {
    __builtin_amdgcn_global_load_lds(
        (const __attribute__((address_space(1))) void*)g,
        (__attribute__((address_space(3))) void*)l, 16, 0, 0);
}

// ------------- fused GEMM + HH: fp32 DMA tiles, convert at LDS-read -------------
// R13: R10-R12 (register staging) all plateaued at 60-63 us: the wave owns the
// load->vmcnt->cvt->ds_write chain, serializing a VMEM drain into every
// iteration with too few waves/CU to cover it (~74K cycles per block measured
// via occupancy=22% => 2 generations). The R0/R8 DMA gemm ran ~19-20 us at the
// same structure. Fix: global_load_lds the fp32 tiles UNCONVERTED; convert to
// bf16 at fragment read (2x ds_read_b128 + cvt_pk per frag, co-issues with
// MFMA). No prefetch VGPRs, no bf16 round-trip, no workspace fill.
//   - 64x64 tiles (fp32 LDS is 2x bf16), grid 2048 = 8/CU, 4 blocks/CU
//     resident (36.9 KB LDS), 2 clean generations.
//   - XOR swizzle at 16B-fp32-chunk granularity on the DMA SOURCE address
//     (LDS[r][c] = global chunk c^(r&7)); reader applies the same involution:
//     frag floats [8c..8c+7] sit at byte (2c^(lr&7))*16 and that ^16.
//     Bank spread: 8 lanes per 4-bank group = free 2-way.
//   - 2 barriers/K-tile (R8's proven DMA structure; dbuf with DMA regressed
//     in R9 via compiler vmcnt(0)-alias drains).
__global__ __launch_bounds__(256, 4)
void snn_dma_kernel(const float* __restrict__ x, const float* __restrict__ W,
                    const float* __restrict__ gNa_p, const float* __restrict__ gK_p,
                    const float* __restrict__ gL_p, float* __restrict__ out)
{
    __shared__ float sWf[64 * 64];     // W-tile fp32: 64 gn rows x 64 k
    __shared__ float sXf[64 * 64];     // x-tile fp32: 64 gm rows x 64 k
    __shared__ float tbl[TBL_N + 1];

    const int tid = threadIdx.x;

    // XCD swizzle: each XCD owns 32 bm tiles; consecutive slots sweep all 8 bn
    // for one bm (x rows stay hot in the XCD's L2 across their 8-fold reuse).
    const int id   = blockIdx.x;            // 0..2047
    const int xcd  = id & 7;
    const int slot = id >> 3;               // 0..255
    const int bm   = xcd * 32 + (slot >> 3);    // 0..255
    const int bn   = slot & 7;                  // 0..7

    const int wv   = tid >> 6;
    const int ln   = tid & 63;
    const int lr   = ln & 15;
    const int quad = ln >> 4;

    // DMA pattern: one issue = 64 lanes x 16B = 4 fp32 rows (256B each).
    // Lane: row-in-group rw4 = ln>>4, chunk ch = ln&15. LDS dest is linear
    // (wave-uniform base + lane*16); swizzle lives on the global source.
    const int rw4  = ln >> 4;               // 0..3
    const int ch   = ln & 15;               // 0..15
    const int rloc = wv * 16 + rw4;         // row in tile (+4j per issue)

    const float* wRow = W + ((long)bn * 64 + rloc) * K_DIM;
    const float* xRow = x + ((long)bm * 64 + rloc) * K_DIM;
    float* wDst = sWf + (wv * 16) * 64;     // + j*4*64 per issue
    float* xDst = sXf + (wv * 16) * 64;

    // ---- prime tile 0 (latency hides under the table build) ----
    #pragma unroll
    for (int j = 0; j < 4; ++j) {
        const int s = (rloc + 4 * j) & 7;
        gl_lds16(wRow + (long)(4 * j) * K_DIM + (ch ^ s) * 4, wDst + j * 4 * 64);
        gl_lds16(xRow + (long)(4 * j) * K_DIM + (ch ^ s) * 4, xDst + j * 4 * 64);
    }

    // ---- exact-HH I_in(V) table ----
    {
        const float gNa = *gNa_p, gK = *gK_p, gL = *gL_p;
        for (int i = tid; i <= TBL_N; i += 256) {
            const float V = -4.0f + (8.0f / TBL_N) * i;
            const float am = 0.1f * (V + 40.0f) / (1.0f - expf(-(V + 40.0f) * 0.1f));
            const float bm_ = 4.0f * expf(-(V + 65.0f) * (1.0f / 18.0f));
            const float ah = 0.07f * expf(-(V + 65.0f) * 0.05f);
            const float bh = 1.0f / (1.0f + expf(-(V + 35.0f) * 0.1f));
            const float an = 0.01f * (V + 55.0f) / (1.0f - expf(-(V + 55.0f) * 0.1f));
            const float bn_ = 0.125f * expf(-(V + 65.0f) * 0.0125f);
            const float m = 0.05f + 0.1f * (am * 0.95f - bm_ * 0.05f);
            const float h = 0.60f + 0.1f * (ah * 0.40f - bh * 0.60f);
            const float n = 0.32f + 0.1f * (an * 0.68f - bn_ * 0.32f);
            tbl[i] = gNa * m * m * m * h * (V - 50.0f)
                   + gK * (n * n) * (n * n) * (V + 77.0f)
                   + gL * (V + 54.4f) + V;
        }
    }
    __syncthreads();   // tile 0 resident (compiler drains vmcnt), tbl built

    f32x4 acc[4] = {};   // 4 gn frags x (16 gm rows owned by this wave)

    for (int t = 0; t < 8; ++t) {
        #pragma unroll
        for (int kk = 0; kk < 2; ++kk) {
            const int cidx = quad + 4 * kk;
            const int b0   = ((2 * cidx) ^ (lr & 7)) * 16;   // byte off in 256B row
            bf16x8 aw[4], bx;
            {   // x frag: row wv*16+lr; floats [8cidx..8cidx+7]
                const char* base = (const char*)(sXf + (wv * 16 + lr) * 64);
                float4 lo = *(const float4*)(base + b0);
                float4 hi = *(const float4*)(base + (b0 ^ 16));
                bx = cvt8(lo, hi);
            }
            #pragma unroll
            for (int f = 0; f < 4; ++f) {   // W frags: rows f*16+lr
                const char* base = (const char*)(sWf + (f * 16 + lr) * 64);
                float4 lo = *(const float4*)(base + b0);
                float4 hi = *(const float4*)(base + (b0 ^ 16));
                aw[f] = cvt8(lo, hi);
            }
            #pragma unroll
            for (int f = 0; f < 4; ++f)
                acc[f] = __builtin_amdgcn_mfma_f32_16x16x32_bf16(
                    aw[f], bx, acc[f], 0, 0, 0);
        }
        if (t < 7) {
            __syncthreads();   // all reads of tile t done
            const int kt = (t + 1) * 64;
            #pragma unroll
            for (int j = 0; j < 4; ++j) {
                const int s = (rloc + 4 * j) & 7;
                gl_lds16(wRow + (long)(4 * j) * K_DIM + kt + (ch ^ s) * 4,
                         wDst + j * 4 * 64);
                gl_lds16(xRow + (long)(4 * j) * K_DIM + kt + (ch ^ s) * 4,
                         xDst + j * 4 * 64);
            }
            __syncthreads();   // vmcnt drain: tile t+1 resident
        }
    }

    // ---- float4 epilogue: 4 consecutive gn per thread per frag ----
    float* outS = out;
    float* outV = out + (long)M_DIM * N_DIM;
    float* outW = out + 2L * M_DIM * N_DIM;

    const long gm = (long)bm * 64 + wv * 16 + lr;
    #pragma unroll
    for (int f = 0; f < 4; ++f) {
        const int gn4 = bn * 64 + f * 16 + quad * 4;
        const long idx = gm * N_DIM + gn4;
        f32x4 vS, vV, vW;
        #pragma unroll
        for (int i = 0; i < 4; ++i) {
            const float V = acc[f][i];
            float u = (V + 4.0f) * (TBL_N / 8.0f);
            u = fminf(fmaxf(u, 0.0f), (float)TBL_N - 0.001f);
            const int   iu = (int)u;
            const float fr = u - (float)iu;
            const float I_in = tbl[iu] + fr * (tbl[iu + 1] - tbl[iu]);
            const float v_new = -65.0f + I_in * 0.005f;
            const float spike = (v_new >= -50.0f) ? 1.0f : 0.0f;
            vS[i] = spike;
            vW[i] = (0.5f * (v_new + 65.0f) + 0.1f * spike) * 0.001f;
            vV[i] = (spike > 0.5f) ? -65.0f : v_new;
        }
        *(f32x4*)(outS + idx) = vS;
        *(f32x4*)(outV + idx) = vV;
        *(f32x4*)(outW + idx) = vW;
    }
}

extern "C" void kernel_launch(void* const* d_in, const int* in_sizes, int n_in,
                              void* d_out, int out_size, void* d_ws, size_t ws_size,
                              hipStream_t stream) {
    const float* x   = (const float*)d_in[0];
    const float* W   = (const float*)d_in[1];
    const float* gNa = (const float*)d_in[2];
    const float* gK  = (const float*)d_in[3];
    const float* gL  = (const float*)d_in[4];
    float* out = (float*)d_out;
    (void)d_ws; (void)ws_size;  // no workspace: avoids its poison-fill cost

    hipLaunchKernelGGL(snn_dma_kernel, dim3(2048), dim3(256), 0, stream,
                       x, W, gNa, gK, gL, out);
}

// Round 5
// 156.971 us; speedup vs baseline: 1.0763x; 1.0763x over previous
//
#include <hip/hip_runtime.h>
#include <hip/hip_bf16.h>
#include <math.h>

typedef __bf16 bf16x4 __attribute__((ext_vector_type(4)));
typedef __bf16 bf16x8 __attribute__((ext_vector_type(8)));
typedef float  f32x4  __attribute__((ext_vector_type(4)));

#define M_DIM 16384
#define N_DIM 512
#define K_DIM 512
#define TBL_N 1024

// LDS row pad: 40 bf16 = 80 B stride = 20 banks (odd*4 mod 32) -> 16-lane
// fragment reads spread 2-way across banks (free), and 80/16=5 keeps every
// b128 16B-aligned. No XOR swizzle needed anywhere.
#define LDP 40

__device__ inline bf16x4 cvt4(float4 a) {
    bf16x4 r;
    r[0] = (__bf16)a.x; r[1] = (__bf16)a.y; r[2] = (__bf16)a.z; r[3] = (__bf16)a.w;
    return r;
}

// ---------------- fused GEMM + HH: M64 x N512(full) x k32 ----------------
// R14: R10-R13 all serialized alternating pipe-phases at 2-3 blocks/CU
// (60-70us, every pipe <50%). Restructure:
//   - N-tile = full 512: x read EXACTLY once (33.5MB HBM, coalesced,
//     reg-prefetched). W (1MB) becomes the reused operand and streams from
//     L2 (256 blocks x 1MB = 256MB L2 ~ 7.7us aggregate = K-loop bound).
//   - grid 256 = 1 block/CU, 512 threads = 8 waves (2m x 4n), wave-tile
//     32m x 128n, acc 64 f32/thread. k-step 32, 16 steps, 2 barriers/step.
//   - Both tiles reg-staged fp32->bf16 (pad-40 rows, conflict-free, no XOR).
//     W prefetch pw[8] (32 VGPR) issued during the PREVIOUS stage phase ->
//     L2 latency hides under the MFMA phase. launch_bounds(512,2): 256-VGPR
//     cap, no spill possible at ~170 live.
//   - Epilogue = the write floor (100.7MB ~ 16us @ measured 6.6TB/s fill BW).
__global__ __launch_bounds__(512, 2)
void snn_fused_kernel(const float* __restrict__ x, const float* __restrict__ W,
                      const float* __restrict__ gNa_p, const float* __restrict__ gK_p,
                      const float* __restrict__ gL_p, float* __restrict__ out)
{
    __shared__ __bf16 sW[512 * LDP];   // W-tile: 512 gn rows x 32 k (pad 40)
    __shared__ __bf16 sX[64 * LDP];    // x-tile:  64 gm rows x 32 k (pad 40)
    __shared__ float  tbl[TBL_N + 1];

    const int tid = threadIdx.x;
    const int bm  = blockIdx.x;            // 0..255, M-tile of 64 rows

    const int wv   = tid >> 6;             // 0..7
    const int ln   = tid & 63;
    const int lr   = ln & 15;
    const int quad = ln >> 4;
    const int wm   = wv >> 2;              // 0..1: m-half (32 rows)
    const int wn   = wv & 3;               // 0..3: n-quarter (128 cols)

    // staging coords: 8 threads per row (8 x 4 floats = 32 k), 64 rows/pass.
    // Per wave: 8 rows x 128B contiguous -> full-line coalesced.
    const int srow = tid >> 3;             // 0..63
    const int sc4  = (tid & 7) * 4;        // float col within k-slice
    const float* wPtr = W + (long)srow * K_DIM + sc4;              // + p*64*512 + kt
    const float* xPtr = x + ((long)bm * 64 + srow) * K_DIM + sc4;  // + kt
    const int wLofs = srow * LDP + sc4;    // + p*64*LDP
    const int xLofs = srow * LDP + sc4;

    // ---- issue step-0 loads (latency hides under the table build) ----
    float4 pw[8];                          // 32 VGPR W prefetch (8 passes x 64 rows)
    float4 px;                             // x prefetch (1 pass of 64 rows)
    #pragma unroll
    for (int p = 0; p < 8; ++p)
        pw[p] = *(const float4*)(wPtr + (long)p * 64 * K_DIM);
    px = *(const float4*)(xPtr);

    // ---- exact-HH I_in(V) table ----
    {
        const float gNa = *gNa_p, gK = *gK_p, gL = *gL_p;
        for (int i = tid; i <= TBL_N; i += 512) {
            const float V = -4.0f + (8.0f / TBL_N) * i;
            const float am = 0.1f * (V + 40.0f) / (1.0f - expf(-(V + 40.0f) * 0.1f));
            const float bm_ = 4.0f * expf(-(V + 65.0f) * (1.0f / 18.0f));
            const float ah = 0.07f * expf(-(V + 65.0f) * 0.05f);
            const float bh = 1.0f / (1.0f + expf(-(V + 35.0f) * 0.1f));
            const float an = 0.01f * (V + 55.0f) / (1.0f - expf(-(V + 55.0f) * 0.1f));
            const float bn_ = 0.125f * expf(-(V + 65.0f) * 0.0125f);
            const float m = 0.05f + 0.1f * (am * 0.95f - bm_ * 0.05f);
            const float h = 0.60f + 0.1f * (ah * 0.40f - bh * 0.60f);
            const float n = 0.32f + 0.1f * (an * 0.68f - bn_ * 0.32f);
            tbl[i] = gNa * m * m * m * h * (V - 50.0f)
                   + gK * (n * n) * (n * n) * (V + 77.0f)
                   + gL * (V + 54.4f) + V;
        }
    }

    // ---- stage step 0, issue step-1 loads ----
    #pragma unroll
    for (int p = 0; p < 8; ++p) {
        float4 v = pw[p];
        pw[p] = *(const float4*)(wPtr + (long)p * 64 * K_DIM + 32);
        *(bf16x4*)(&sW[wLofs + p * 64 * LDP]) = cvt4(v);
    }
    {
        float4 v = px;
        px = *(const float4*)(xPtr + 32);
        *(bf16x4*)(&sX[xLofs]) = cvt4(v);
    }
    __syncthreads();   // tile 0 resident, tbl built

    f32x4 acc[8][2] = {};   // [n frag nf][m frag mf]

    for (int t = 0; t < 16; ++t) {
        // ---- MFMA phase on resident tile (pw/px for t+1 in flight) ----
        {
            const int ko = quad * 8;       // lane's 8 k-elems within the 32-k step
            bf16x8 a[8], b[2];
            #pragma unroll
            for (int nf = 0; nf < 8; ++nf)
                a[nf] = *(const bf16x8*)(&sW[(wn * 128 + nf * 16 + lr) * LDP + ko]);
            #pragma unroll
            for (int mf = 0; mf < 2; ++mf)
                b[mf] = *(const bf16x8*)(&sX[(wm * 32 + mf * 16 + lr) * LDP + ko]);
            #pragma unroll
            for (int nf = 0; nf < 8; ++nf)
                #pragma unroll
                for (int mf = 0; mf < 2; ++mf)
                    acc[nf][mf] = __builtin_amdgcn_mfma_f32_16x16x32_bf16(
                        a[nf], b[mf], acc[nf][mf], 0, 0, 0);
        }
        if (t < 15) {
            __syncthreads();   // all reads of tile t done
            const int nk = (t + 2) * 32;
            #pragma unroll
            for (int p = 0; p < 8; ++p) {
                float4 v = pw[p];
                if (t < 14)
                    pw[p] = *(const float4*)(wPtr + (long)p * 64 * K_DIM + nk);
                *(bf16x4*)(&sW[wLofs + p * 64 * LDP]) = cvt4(v);
            }
            {
                float4 v = px;
                if (t < 14)
                    px = *(const float4*)(xPtr + nk);
                *(bf16x4*)(&sX[xLofs]) = cvt4(v);
            }
            __syncthreads();   // tile t+1 resident
        }
    }

    // ---- epilogue: HH via table, float4 stores (4 consecutive gn/thread) ----
    float* outS = out;
    float* outV = out + (long)M_DIM * N_DIM;
    float* outW = out + 2L * M_DIM * N_DIM;

    #pragma unroll
    for (int nf = 0; nf < 8; ++nf) {
        const int gn0 = wn * 128 + nf * 16 + quad * 4;
        #pragma unroll
        for (int mf = 0; mf < 2; ++mf) {
            const long gm  = (long)bm * 64 + wm * 32 + mf * 16 + lr;
            const long idx = gm * N_DIM + gn0;
            f32x4 vS, vV, vW;
            #pragma unroll
            for (int i = 0; i < 4; ++i) {
                const float V = acc[nf][mf][i];
                float u = (V + 4.0f) * (TBL_N / 8.0f);
                u = fminf(fmaxf(u, 0.0f), (float)TBL_N - 0.001f);
                const int   iu = (int)u;
                const float fr = u - (float)iu;
                const float I_in = tbl[iu] + fr * (tbl[iu + 1] - tbl[iu]);
                const float v_new = -65.0f + I_in * 0.005f;
                const float spike = (v_new >= -50.0f) ? 1.0f : 0.0f;
                vS[i] = spike;
                vW[i] = (0.5f * (v_new + 65.0f) + 0.1f * spike) * 0.001f;
                vV[i] = (spike > 0.5f) ? -65.0f : v_new;
            }
            *(f32x4*)(outS + idx) = vS;
            *(f32x4*)(outV + idx) = vV;
            *(f32x4*)(outW + idx) = vW;
        }
    }
}

extern "C" void kernel_launch(void* const* d_in, const int* in_sizes, int n_in,
                              void* d_out, int out_size, void* d_ws, size_t ws_size,
                              hipStream_t stream) {
    const float* x   = (const float*)d_in[0];
    const float* W   = (const float*)d_in[1];
    const float* gNa = (const float*)d_in[2];
    const float* gK  = (const float*)d_in[3];
    const float* gL  = (const float*)d_in[4];
    float* out = (float*)d_out;
    (void)d_ws; (void)ws_size;  // no workspace: avoids its poison-fill cost

    hipLaunchKernelGGL(snn_fused_kernel, dim3(256), dim3(512), 0, stream,
                       x, W, gNa, gK, gL, out);
}